// Round 5
// baseline (392.941 us; speedup 1.0000x reference)
//
#include <hip/hip_runtime.h>
#include <hip/hip_bf16.h>

typedef __attribute__((ext_vector_type(8))) short short8;
typedef __attribute__((ext_vector_type(4))) float f32x4;

// SCALE * log2(e), folded into Ql at store time; flash uses exp2 directly.
#define QSCALE 0.18033688011112042f

__device__ __forceinline__ unsigned short f2bf(float f){
    unsigned u = __float_as_uint(f);
    unsigned r = (u + 0x7fffu + ((u>>16)&1u))>>16;
    return (unsigned short)r;
}
__device__ __forceinline__ unsigned pk_rtne(float hi, float lo){
    return (((unsigned)f2bf(hi))<<16) | (unsigned)f2bf(lo);
}

// ---------------- fused prep+gemm: out = xl+xr; T1/T2 = dwconv-input conv1x1 outputs, both sides ----
// (unchanged from R2 - measured good: kills 67MB Xt round-trip, total 324->309us)
__global__ __launch_bounds__(256) void prepgemm_k(const float* __restrict__ xl,
                                                  const float* __restrict__ xr,
                                                  float* __restrict__ out,
                                                  const float* __restrict__ wAL, const float* __restrict__ bAL,
                                                  const float* __restrict__ wBL, const float* __restrict__ bBL,
                                                  const float* __restrict__ wAR, const float* __restrict__ bAR,
                                                  const float* __restrict__ wBR, const float* __restrict__ bBR,
                                                  unsigned short* __restrict__ T1L, unsigned short* __restrict__ T2L,
                                                  unsigned short* __restrict__ T1R, unsigned short* __restrict__ T2R){
    __shared__ float ftA[64*130];
    __shared__ __align__(16) short sB[128*72];
    __shared__ float sbias[128];

    int bid = blockIdx.x;
    int b = bid >> 9, px0 = (bid & 511) << 7;
    int tid = threadIdx.x;
    int wv = tid>>6, lane = tid&63, quad = lane>>4, l16 = lane&15;

    // ---- phase 1: load xl+xr strip, write out, stage xl (fp32) + weights L ----
    float4 vxr[8];
    #pragma unroll
    for (int it=0; it<8; it++){
        int lin = it*256 + tid;             // 2048 float4 = 64c x 128px
        int c = lin >> 5, piece = lin & 31;
        size_t off = (((size_t)(b*64 + c))<<16) + px0 + piece*4;
        float4 va = *(const float4*)(xl + off);
        float4 vb = *(const float4*)(xr + off);
        vxr[it] = vb;
        float4 vo; vo.x=va.x+vb.x; vo.y=va.y+vb.y; vo.z=va.z+vb.z; vo.w=va.w+vb.w;
        *(float4*)(out + off) = vo;
        float* d = ftA + c*130 + piece*4;
        float2 lo; lo.x=va.x; lo.y=va.y;
        float2 hi; hi.x=va.z; hi.y=va.w;
        *(float2*)(d) = lo;
        *(float2*)(d+2) = hi;
    }
    {   // weights L -> sB (128 out x 64 in, bf16, pitch 72)
        #pragma unroll
        for (int it=0; it<8; it++){
            int lin = it*256 + tid;          // 2048 float4 = 8192 floats
            int o = lin >> 4, cc4 = (lin & 15) << 2;
            const float* wsrc = (o < 64) ? (wAL + o*64 + cc4) : (wBL + (o-64)*64 + cc4);
            float4 w4 = *(const float4*)wsrc;
            uint2 v; v.x = pk_rtne(w4.y, w4.x); v.y = pk_rtne(w4.w, w4.z);
            *(uint2*)(sB + o*72 + cc4) = v;
        }
        if (tid < 128) sbias[tid] = (tid < 64) ? bAL[tid] : bBL[tid-64];
    }
    __syncthreads();

    const f32x4 z4 = {0.f,0.f,0.f,0.f};

    // ---- per-side GEMM macro body (wave owns 32 px rows: wv*32 + mt*16 + l16) ----
    #define DO_GEMM(T1p, T2p) do {                                                  \
        short8 a0[2], a1[2];                                                        \
        _Pragma("unroll")                                                           \
        for (int mt=0; mt<2; mt++){                                                 \
            int pxr = wv*32 + mt*16 + l16;                                          \
            _Pragma("unroll")                                                       \
            for (int j=0;j<8;j++){                                                  \
                a0[mt][j] = (short)f2bf(ftA[(quad*8 + j)*130 + pxr]);               \
                a1[mt][j] = (short)f2bf(ftA[(32 + quad*8 + j)*130 + pxr]);          \
            }                                                                       \
        }                                                                           \
        _Pragma("unroll")                                                           \
        for (int set=0; set<2; set++){                                              \
            unsigned short* T = set ? (T2p) : (T1p);                                \
            short8 bB0[4], bB1[4];                                                  \
            _Pragma("unroll")                                                       \
            for (int nt=0; nt<4; nt++){                                             \
                bB0[nt] = *(const short8*)(sB + (set*64 + nt*16 + l16)*72 + quad*8);      \
                bB1[nt] = *(const short8*)(sB + (set*64 + nt*16 + l16)*72 + 32 + quad*8); \
            }                                                                       \
            _Pragma("unroll")                                                       \
            for (int nt=0; nt<4; nt++){                                             \
                float4 b4 = *(const float4*)(sbias + set*64 + nt*16 + quad*4);      \
                _Pragma("unroll")                                                   \
                for (int mt=0; mt<2; mt++){                                         \
                    f32x4 acc = __builtin_amdgcn_mfma_f32_16x16x32_bf16(bB0[nt], a0[mt], z4, 0,0,0); \
                    acc       = __builtin_amdgcn_mfma_f32_16x16x32_bf16(bB1[nt], a1[mt], acc, 0,0,0); \
                    uint2 v;                                                        \
                    v.x = pk_rtne(acc[1]+b4.y, acc[0]+b4.x);                        \
                    v.y = pk_rtne(acc[3]+b4.w, acc[2]+b4.z);                        \
                    int px = px0 + wv*32 + mt*16 + l16;                             \
                    *(uint2*)(T + (size_t)px*64 + nt*16 + quad*4) = v;              \
                }                                                                   \
            }                                                                       \
        }                                                                           \
    } while(0)

    // ---- phase 2: GEMM side L ----
    DO_GEMM(T1L + ((size_t)b<<22), T2L + ((size_t)b<<22));
    __syncthreads();

    // ---- phase 3: restage xr + weights R ----
    #pragma unroll
    for (int it=0; it<8; it++){
        int lin = it*256 + tid;
        int c = lin >> 5, piece = lin & 31;
        float4 vb = vxr[it];
        float* d = ftA + c*130 + piece*4;
        float2 lo; lo.x=vb.x; lo.y=vb.y;
        float2 hi; hi.x=vb.z; hi.y=vb.w;
        *(float2*)(d) = lo;
        *(float2*)(d+2) = hi;
    }
    {
        #pragma unroll
        for (int it=0; it<8; it++){
            int lin = it*256 + tid;
            int o = lin >> 4, cc4 = (lin & 15) << 2;
            const float* wsrc = (o < 64) ? (wAR + o*64 + cc4) : (wBR + (o-64)*64 + cc4);
            float4 w4 = *(const float4*)wsrc;
            uint2 v; v.x = pk_rtne(w4.y, w4.x); v.y = pk_rtne(w4.w, w4.z);
            *(uint2*)(sB + o*72 + cc4) = v;
        }
        if (tid < 128) sbias[tid] = (tid < 64) ? bAR[tid] : bBR[tid-64];
    }
    __syncthreads();

    // ---- phase 4: GEMM side R ----
    DO_GEMM(T1R + ((size_t)b<<22), T2R + ((size_t)b<<22));
    #undef DO_GEMM
}

// ---------------- dual depthwise 3x3: T1->Q (scaled, [b,hw,c]), T2->V ([b,c,hw]) ----------------
__device__ __forceinline__ void dw_tile(const unsigned short* __restrict__ Tb,
                                        const float* __restrict__ wd,
                                        const float* __restrict__ bd,
                                        int c0, int w0, int h, float acc[4][4]){
    #pragma unroll
    for (int ch=0; ch<4; ch++){
        float bv = bd[c0+ch];
        #pragma unroll
        for (int i=0;i<4;i++) acc[ch][i] = bv;
    }
    #pragma unroll
    for (int dh=-1; dh<=1; dh++){
        int hh = h + dh;
        if (hh < 0 || hh > 127) continue;
        const unsigned short* Tr = Tb + ((size_t)(hh*512))*64 + c0;
        float win[6][4];
        #pragma unroll
        for (int j=0;j<6;j++){
            int ww = w0 - 1 + j;
            if (ww >= 0 && ww < 512){
                uint2 v = *(const uint2*)(Tr + (size_t)ww*64);
                win[j][0] = __uint_as_float(v.x<<16);
                win[j][1] = __uint_as_float(v.x & 0xffff0000u);
                win[j][2] = __uint_as_float(v.y<<16);
                win[j][3] = __uint_as_float(v.y & 0xffff0000u);
            } else {
                win[j][0]=0.f; win[j][1]=0.f; win[j][2]=0.f; win[j][3]=0.f;
            }
        }
        #pragma unroll
        for (int ch=0; ch<4; ch++){
            float k0 = wd[(c0+ch)*9 + (dh+1)*3];
            float k1 = wd[(c0+ch)*9 + (dh+1)*3 + 1];
            float k2 = wd[(c0+ch)*9 + (dh+1)*3 + 2];
            #pragma unroll
            for (int i=0;i<4;i++)
                acc[ch][i] += k0*win[i][ch] + k1*win[i+1][ch] + k2*win[i+2][ch];
        }
    }
}

__global__ __launch_bounds__(256) void dwconv_k(const unsigned short* __restrict__ T1,
                                                const unsigned short* __restrict__ T2,
                                                const float* __restrict__ wd1,
                                                const float* __restrict__ bd1,
                                                const float* __restrict__ wd2,
                                                const float* __restrict__ bd2,
                                                unsigned short* __restrict__ Qdst,
                                                unsigned short* __restrict__ Vdst,
                                                float qscale){
    int bid = blockIdx.x;
    int wt = bid & 7, h = (bid>>3)&127, b = bid>>10;
    int tid = threadIdx.x;
    int cg = tid & 15, wl = tid >> 4;
    int c0 = cg*4;
    int w0 = wt*64 + wl*4;
    float acc[4][4];   // [ch][w]
    dw_tile(T1 + ((size_t)b<<22), wd1, bd1, c0, w0, h, acc);
    {
        int base = (b*128 + h)*512;
        #pragma unroll
        for (int i=0;i<4;i++){
            uint2 v;
            v.x = pk_rtne(acc[1][i]*qscale, acc[0][i]*qscale);
            v.y = pk_rtne(acc[3][i]*qscale, acc[2][i]*qscale);
            *(uint2*)(Qdst + ((size_t)(base + w0 + i))*64 + c0) = v;
        }
    }
    dw_tile(T2 + ((size_t)b<<22), wd2, bd2, c0, w0, h, acc);
    {
        #pragma unroll
        for (int ch=0; ch<4; ch++){
            uint2 v;
            v.x = pk_rtne(acc[ch][1], acc[ch][0]);
            v.y = pk_rtne(acc[ch][3], acc[ch][2]);
            *(uint2*)(Vdst + (((size_t)(b*64 + c0 + ch))<<16) + h*512 + w0) = v;
        }
    }
}

// ---------------- flash attention + fused output conv1x1, atomic add into out ----------------
// R4 change: NO K/V LDS staging, NO barriers. K- and V-fragments are wave-invariant and the
// per-(dir,b,h) K/V set (128 KB) is shared by the 4 co-XCD q-tile blocks -> L2-resident.
// Fragments read directly from global/L2; sP/sFA/sOT are per-wave regions so the kernel has
// ZERO __syncthreads. Waves run free; 16 waves/CU TLP hides L2 latency (m169 precedent).
#define PP 72
#define PFA 72
#define POT 17
#define OFF_P   0        // 128*72*2 = 18432 (sP, aliased by sFA in epilogue; per-wave 32-row slices)
#define OFF_OT  18432    // 4*64*17*4 = 17408 (sOT, per-wave slices)
#define LDS_TOT 35840

__global__ __launch_bounds__(256) void flash_k(
    const unsigned short* __restrict__ Ql, const unsigned short* __restrict__ Qr,
    const unsigned short* __restrict__ Vl, const unsigned short* __restrict__ Vr,
    const float* __restrict__ lw3, const float* __restrict__ lb3,
    const float* __restrict__ rw3, const float* __restrict__ rb3,
    float* __restrict__ out)
{
    __shared__ __align__(16) char smem[LDS_TOT];
    short* sP  = (short*)(smem + OFF_P);   // per-wave 32-row slices
    short* sFA = (short*)(smem + OFF_P);   // alias (epilogue, same wave rows)
    float* sOT = (float*)(smem + OFF_OT);  // per-wave slices

    // XCD swizzle: 4 q-tiles of one (dir,b,h) share bid%8 within a 32-block window.
    int bid = blockIdx.x;
    int g  = ((bid >> 5) << 3) | (bid & 7);   // 0..511 = dir*256 + b*128 + h
    int qt = (bid >> 3) & 3;
    int h = g & 127, b = (g >> 7) & 1, dir = g >> 8;
    const unsigned short *Qg, *Kg, *Vg; const float *w3, *b3;
    if (dir==0){ Qg = Ql; Kg = Qr; Vg = Vr; w3 = lw3; b3 = lb3; }
    else       { Qg = Qr; Kg = Ql; Vg = Vl; w3 = rw3; b3 = rb3; }

    int tid = threadIdx.x;
    int wv = tid>>6, lane = tid&63, quad = lane>>4, l16 = lane&15;
    int bh = b*128 + h;

    // Q fragments: direct global loads (wave-private rows; coalesced)
    short8 aq0[2], aq1[2];
    #pragma unroll
    for (int s=0; s<2; s++){
        size_t qrow = ((size_t)bh*512 + qt*128 + wv*32 + s*16 + l16)*64;
        aq0[s] = *(const short8*)(Qg + qrow + quad*8);
        aq1[s] = *(const short8*)(Qg + qrow + 32 + quad*8);
    }

    const f32x4 z4 = {0.f,0.f,0.f,0.f};
    f32x4 oacc[2][4];
    #pragma unroll
    for (int s=0; s<2; s++)
        #pragma unroll
        for (int ct=0; ct<4; ct++) oacc[s][ct] = z4;
    float lps[2] = {0.f, 0.f};

    const unsigned short* Kbase = Kg + (size_t)bh*512*64;          // [kv][c]
    const unsigned short* Vbase = Vg + ((size_t)(b*64)*128 + h)*512; // [c][hw], col = w

    for (int kt=0; kt<8; kt++){
        // K fragments direct from global/L2 (wave-invariant; 4 co-XCD blocks share -> L2 hits)
        short8 bk0[4], bk1[4];
        #pragma unroll
        for (int nt=0; nt<4; nt++){
            const unsigned short* kr = Kbase + (size_t)(kt*64 + nt*16 + l16)*64;
            bk0[nt] = *(const short8*)(kr + quad*8);
            bk1[nt] = *(const short8*)(kr + 32 + quad*8);
        }
        // S^T = K Q^T per q-subtile: D[row=key=nt*16+quad*4+r][col=q=l16]
        #pragma unroll
        for (int nt=0; nt<4; nt++){
            #pragma unroll
            for (int s=0; s<2; s++){
                __builtin_amdgcn_s_setprio(1);
                f32x4 sv = __builtin_amdgcn_mfma_f32_16x16x32_bf16(bk0[nt], aq0[s], z4, 0,0,0);
                sv       = __builtin_amdgcn_mfma_f32_16x16x32_bf16(bk1[nt], aq1[s], sv, 0,0,0);
                __builtin_amdgcn_s_setprio(0);
                float p0 = __builtin_amdgcn_exp2f(sv[0]);
                float p1 = __builtin_amdgcn_exp2f(sv[1]);
                float p2 = __builtin_amdgcn_exp2f(sv[2]);
                float p3 = __builtin_amdgcn_exp2f(sv[3]);
                lps[s] += (p0+p1) + (p2+p3);
                unsigned lo = __builtin_amdgcn_perm(__float_as_uint(p1), __float_as_uint(p0), 0x07060302);
                unsigned hi = __builtin_amdgcn_perm(__float_as_uint(p3), __float_as_uint(p2), 0x07060302);
                uint2 pv; pv.x = lo; pv.y = hi;
                *(uint2*)(sP + (wv*32 + s*16 + l16)*PP + nt*16 + quad*4) = pv;
            }
        }
        // same-wave LDS write->read: no barrier needed (per-wave region)
        short8 ap0[2], ap1[2];
        #pragma unroll
        for (int s=0; s<2; s++){
            ap0[s] = *(const short8*)(sP + (wv*32 + s*16 + l16)*PP + quad*8);
            ap1[s] = *(const short8*)(sP + (wv*32 + s*16 + l16)*PP + 32 + quad*8);
        }
        __builtin_amdgcn_s_setprio(1);
        #pragma unroll
        for (int ct=0; ct<4; ct++){
            // V fragments direct from global/L2: channel = ct*16+l16, kv = kt*64 + {0,32}+quad*8
            const unsigned short* vr = Vbase + (size_t)(ct*16 + l16)*65536 + kt*64;
            short8 bv0 = *(const short8*)(vr + quad*8);
            short8 bv1 = *(const short8*)(vr + 32 + quad*8);
            #pragma unroll
            for (int s=0; s<2; s++){
                oacc[s][ct] = __builtin_amdgcn_mfma_f32_16x16x32_bf16(ap0[s], bv0, oacc[s][ct], 0,0,0);
                oacc[s][ct] = __builtin_amdgcn_mfma_f32_16x16x32_bf16(ap1[s], bv1, oacc[s][ct], 0,0,0);
            }
        }
        __builtin_amdgcn_s_setprio(0);
    }

    // l(q) reduction
    float inv[2][4];
    #pragma unroll
    for (int s=0; s<2; s++){
        float l = lps[s];
        l += __shfl_xor(l, 16);
        l += __shfl_xor(l, 32);
        #pragma unroll
        for (int r=0;r<4;r++) inv[s][r] = 1.0f / __shfl(l, quad*4 + r);
    }

    // epilogue: F -> LDS (A layout, per-wave rows), conv1x1 MFMA with W3 frags from global,
    // bias, per-wave LDS transpose, atomic add. No cross-wave hazards -> no barriers.
    #pragma unroll
    for (int s=0; s<2; s++){
        short* sFw = sFA + (wv*32 + s*16)*PFA;
        #pragma unroll
        for (int ct=0; ct<4; ct++){
            #pragma unroll
            for (int r=0;r<4;r++)
                sFw[(quad*4+r)*PFA + ct*16 + l16] = (short)f2bf(oacc[s][ct][r]*inv[s][r]);
        }
    }
    short8 af0[2], af1[2];
    #pragma unroll
    for (int s=0; s<2; s++){
        af0[s] = *(const short8*)(sFA + (wv*32 + s*16 + l16)*PFA + quad*8);
        af1[s] = *(const short8*)(sFA + (wv*32 + s*16 + l16)*PFA + 32 + quad*8);
    }
    f32x4 d2[2][4];
    #pragma unroll
    for (int ot=0; ot<4; ot++){
        const float* wrow = w3 + (ot*16 + l16)*64 + quad*8;
        float4 wa = *(const float4*)(wrow);
        float4 wb = *(const float4*)(wrow + 4);
        float4 wc = *(const float4*)(wrow + 32);
        float4 wd = *(const float4*)(wrow + 36);
        short8 bw0, bw1;
        bw0[0]=(short)f2bf(wa.x); bw0[1]=(short)f2bf(wa.y); bw0[2]=(short)f2bf(wa.z); bw0[3]=(short)f2bf(wa.w);
        bw0[4]=(short)f2bf(wb.x); bw0[5]=(short)f2bf(wb.y); bw0[6]=(short)f2bf(wb.z); bw0[7]=(short)f2bf(wb.w);
        bw1[0]=(short)f2bf(wc.x); bw1[1]=(short)f2bf(wc.y); bw1[2]=(short)f2bf(wc.z); bw1[3]=(short)f2bf(wc.w);
        bw1[4]=(short)f2bf(wd.x); bw1[5]=(short)f2bf(wd.y); bw1[6]=(short)f2bf(wd.z); bw1[7]=(short)f2bf(wd.w);
        float bias = b3[ot*16 + l16];
        #pragma unroll
        for (int s=0; s<2; s++){
            d2[s][ot] = __builtin_amdgcn_mfma_f32_16x16x32_bf16(af0[s], bw0, z4, 0,0,0);
            d2[s][ot] = __builtin_amdgcn_mfma_f32_16x16x32_bf16(af1[s], bw1, d2[s][ot], 0,0,0);
            #pragma unroll
            for (int r=0;r<4;r++) d2[s][ot][r] += bias;
        }
    }
    float* sOw = sOT + wv*(64*POT);
    #pragma unroll
    for (int s=0; s<2; s++){
        #pragma unroll
        for (int ot=0; ot<4; ot++){
            #pragma unroll
            for (int r=0;r<4;r++)
                sOw[(ot*16 + l16)*POT + quad*4 + r] = d2[s][ot][r];
        }
        int qbase = qt*128 + wv*32 + s*16;
        #pragma unroll
        for (int it=0; it<16; it++){
            int o = it*4 + quad;
            float val = sOw[o*POT + l16];
            unsafeAtomicAdd(out + ((size_t)(b*64 + o)*128 + h)*512 + qbase + l16, val);
        }
    }
}

extern "C" void kernel_launch(void* const* d_in, const int* in_sizes, int n_in,
                              void* d_out, int out_size, void* d_ws, size_t ws_size,
                              hipStream_t stream)
{
    const float* xl = (const float*)d_in[0];
    const float* xr = (const float*)d_in[1];
    const float* lp1_w1 = (const float*)d_in[2];
    const float* lp1_b1 = (const float*)d_in[3];
    const float* lp1_wd = (const float*)d_in[4];
    const float* lp1_bd = (const float*)d_in[5];
    const float* rp1_w1 = (const float*)d_in[6];
    const float* rp1_b1 = (const float*)d_in[7];
    const float* rp1_wd = (const float*)d_in[8];
    const float* rp1_bd = (const float*)d_in[9];
    const float* lp2_w1 = (const float*)d_in[10];
    const float* lp2_b1 = (const float*)d_in[11];
    const float* lp2_wd = (const float*)d_in[12];
    const float* lp2_bd = (const float*)d_in[13];
    const float* rp2_w1 = (const float*)d_in[14];
    const float* rp2_b1 = (const float*)d_in[15];
    const float* rp2_wd = (const float*)d_in[16];
    const float* rp2_bd = (const float*)d_in[17];
    const float* lp3_w  = (const float*)d_in[18];
    const float* lp3_b  = (const float*)d_in[19];
    const float* rp3_w  = (const float*)d_in[20];
    const float* rp3_b  = (const float*)d_in[21];
    float* out = (float*)d_out;

    // 6 slots of 16 MiB (96 MiB). Choreography (no Xt intermediate):
    //  prepgemm: writes T1L->s2, T2L->s3, T1R->s4, T2R->s5  (s0,s1 free)
    //  dwL: reads s2,s3 -> Ql s0, Vl s1
    //  dwR: reads s4,s5 -> Qr s2, Vr s3 (T1L/T2L dead after dwL)
    //  flash: reads s0,s2,s1,s3
    const size_t S = 16777216;
    char* ws = (char*)d_ws;
    unsigned short* s0 = (unsigned short*)(ws);
    unsigned short* s1 = (unsigned short*)(ws + 1*S);
    unsigned short* s2 = (unsigned short*)(ws + 2*S);
    unsigned short* s3 = (unsigned short*)(ws + 3*S);
    unsigned short* s4 = (unsigned short*)(ws + 4*S);
    unsigned short* s5 = (unsigned short*)(ws + 5*S);

    prepgemm_k<<<1024, 256, 0, stream>>>(xl, xr, out,
        lp1_w1, lp1_b1, lp2_w1, lp2_b1,
        rp1_w1, rp1_b1, rp2_w1, rp2_b1,
        /*T1L*/s2, /*T2L*/s3, /*T1R*/s4, /*T2R*/s5);

    dwconv_k<<<2048, 256, 0, stream>>>(/*T1L*/s2, /*T2L*/s3,
        lp1_wd, lp1_bd, lp2_wd, lp2_bd, /*Ql*/s0, /*Vl*/s1, QSCALE);

    dwconv_k<<<2048, 256, 0, stream>>>(/*T1R*/s4, /*T2R*/s5,
        rp1_wd, rp1_bd, rp2_wd, rp2_bd, /*Qr*/s2, /*Vr*/s3, 1.0f);

    flash_k<<<2048, 256, 0, stream>>>(/*Ql*/s0, /*Qr*/s2, /*Vl*/s1, /*Vr*/s3,
        lp3_w, lp3_b, rp3_w, rp3_b, out);
}

// Round 7
// 303.296 us; speedup vs baseline: 1.2956x; 1.2956x over previous
//
#include <hip/hip_runtime.h>
#include <hip/hip_bf16.h>

typedef __attribute__((ext_vector_type(8))) short short8;
typedef __attribute__((ext_vector_type(4))) float f32x4;

// SCALE * log2(e), folded into Ql at store time; flash uses exp2 directly.
#define QSCALE 0.18033688011112042f

__device__ __forceinline__ unsigned short f2bf(float f){
    unsigned u = __float_as_uint(f);
    unsigned r = (u + 0x7fffu + ((u>>16)&1u))>>16;
    return (unsigned short)r;
}
__device__ __forceinline__ unsigned pk_rtne(float hi, float lo){
    return (((unsigned)f2bf(hi))<<16) | (unsigned)f2bf(lo);
}

// ---------------- fused prep+gemm: out = xl+xr; T1/T2 = dwconv-input conv1x1 outputs, both sides ----
// (unchanged - measured good: kills 67MB Xt round-trip, total 324->309us)
__global__ __launch_bounds__(256) void prepgemm_k(const float* __restrict__ xl,
                                                  const float* __restrict__ xr,
                                                  float* __restrict__ out,
                                                  const float* __restrict__ wAL, const float* __restrict__ bAL,
                                                  const float* __restrict__ wBL, const float* __restrict__ bBL,
                                                  const float* __restrict__ wAR, const float* __restrict__ bAR,
                                                  const float* __restrict__ wBR, const float* __restrict__ bBR,
                                                  unsigned short* __restrict__ T1L, unsigned short* __restrict__ T2L,
                                                  unsigned short* __restrict__ T1R, unsigned short* __restrict__ T2R){
    __shared__ float ftA[64*130];
    __shared__ __align__(16) short sB[128*72];
    __shared__ float sbias[128];

    int bid = blockIdx.x;
    int b = bid >> 9, px0 = (bid & 511) << 7;
    int tid = threadIdx.x;
    int wv = tid>>6, lane = tid&63, quad = lane>>4, l16 = lane&15;

    // ---- phase 1: load xl+xr strip, write out, stage xl (fp32) + weights L ----
    float4 vxr[8];
    #pragma unroll
    for (int it=0; it<8; it++){
        int lin = it*256 + tid;             // 2048 float4 = 64c x 128px
        int c = lin >> 5, piece = lin & 31;
        size_t off = (((size_t)(b*64 + c))<<16) + px0 + piece*4;
        float4 va = *(const float4*)(xl + off);
        float4 vb = *(const float4*)(xr + off);
        vxr[it] = vb;
        float4 vo; vo.x=va.x+vb.x; vo.y=va.y+vb.y; vo.z=va.z+vb.z; vo.w=va.w+vb.w;
        *(float4*)(out + off) = vo;
        float* d = ftA + c*130 + piece*4;
        float2 lo; lo.x=va.x; lo.y=va.y;
        float2 hi; hi.x=va.z; hi.y=va.w;
        *(float2*)(d) = lo;
        *(float2*)(d+2) = hi;
    }
    {   // weights L -> sB (128 out x 64 in, bf16, pitch 72)
        #pragma unroll
        for (int it=0; it<8; it++){
            int lin = it*256 + tid;          // 2048 float4 = 8192 floats
            int o = lin >> 4, cc4 = (lin & 15) << 2;
            const float* wsrc = (o < 64) ? (wAL + o*64 + cc4) : (wBL + (o-64)*64 + cc4);
            float4 w4 = *(const float4*)wsrc;
            uint2 v; v.x = pk_rtne(w4.y, w4.x); v.y = pk_rtne(w4.w, w4.z);
            *(uint2*)(sB + o*72 + cc4) = v;
        }
        if (tid < 128) sbias[tid] = (tid < 64) ? bAL[tid] : bBL[tid-64];
    }
    __syncthreads();

    const f32x4 z4 = {0.f,0.f,0.f,0.f};

    // ---- per-side GEMM macro body (wave owns 32 px rows: wv*32 + mt*16 + l16) ----
    #define DO_GEMM(T1p, T2p) do {                                                  \
        short8 a0[2], a1[2];                                                        \
        _Pragma("unroll")                                                           \
        for (int mt=0; mt<2; mt++){                                                 \
            int pxr = wv*32 + mt*16 + l16;                                          \
            _Pragma("unroll")                                                       \
            for (int j=0;j<8;j++){                                                  \
                a0[mt][j] = (short)f2bf(ftA[(quad*8 + j)*130 + pxr]);               \
                a1[mt][j] = (short)f2bf(ftA[(32 + quad*8 + j)*130 + pxr]);          \
            }                                                                       \
        }                                                                           \
        _Pragma("unroll")                                                           \
        for (int set=0; set<2; set++){                                              \
            unsigned short* T = set ? (T2p) : (T1p);                                \
            short8 bB0[4], bB1[4];                                                  \
            _Pragma("unroll")                                                       \
            for (int nt=0; nt<4; nt++){                                             \
                bB0[nt] = *(const short8*)(sB + (set*64 + nt*16 + l16)*72 + quad*8);      \
                bB1[nt] = *(const short8*)(sB + (set*64 + nt*16 + l16)*72 + 32 + quad*8); \
            }                                                                       \
            _Pragma("unroll")                                                       \
            for (int nt=0; nt<4; nt++){                                             \
                float4 b4 = *(const float4*)(sbias + set*64 + nt*16 + quad*4);      \
                _Pragma("unroll")                                                   \
                for (int mt=0; mt<2; mt++){                                         \
                    f32x4 acc = __builtin_amdgcn_mfma_f32_16x16x32_bf16(bB0[nt], a0[mt], z4, 0,0,0); \
                    acc       = __builtin_amdgcn_mfma_f32_16x16x32_bf16(bB1[nt], a1[mt], acc, 0,0,0); \
                    uint2 v;                                                        \
                    v.x = pk_rtne(acc[1]+b4.y, acc[0]+b4.x);                        \
                    v.y = pk_rtne(acc[3]+b4.w, acc[2]+b4.z);                        \
                    int px = px0 + wv*32 + mt*16 + l16;                             \
                    *(uint2*)(T + (size_t)px*64 + nt*16 + quad*4) = v;              \
                }                                                                   \
            }                                                                       \
        }                                                                           \
    } while(0)

    // ---- phase 2: GEMM side L ----
    DO_GEMM(T1L + ((size_t)b<<22), T2L + ((size_t)b<<22));
    __syncthreads();

    // ---- phase 3: restage xr + weights R ----
    #pragma unroll
    for (int it=0; it<8; it++){
        int lin = it*256 + tid;
        int c = lin >> 5, piece = lin & 31;
        float4 vb = vxr[it];
        float* d = ftA + c*130 + piece*4;
        float2 lo; lo.x=vb.x; lo.y=vb.y;
        float2 hi; hi.x=vb.z; hi.y=vb.w;
        *(float2*)(d) = lo;
        *(float2*)(d+2) = hi;
    }
    {
        #pragma unroll
        for (int it=0; it<8; it++){
            int lin = it*256 + tid;
            int o = lin >> 4, cc4 = (lin & 15) << 2;
            const float* wsrc = (o < 64) ? (wAR + o*64 + cc4) : (wBR + (o-64)*64 + cc4);
            float4 w4 = *(const float4*)wsrc;
            uint2 v; v.x = pk_rtne(w4.y, w4.x); v.y = pk_rtne(w4.w, w4.z);
            *(uint2*)(sB + o*72 + cc4) = v;
        }
        if (tid < 128) sbias[tid] = (tid < 64) ? bAR[tid] : bBR[tid-64];
    }
    __syncthreads();

    // ---- phase 4: GEMM side R ----
    DO_GEMM(T1R + ((size_t)b<<22), T2R + ((size_t)b<<22));
    #undef DO_GEMM
}

// ---------------- dual depthwise 3x3 with 4-h strip + rolling row window ----------------
// R5 change: each block does HB=4 h-rows (grid 2048->512). Rolling 3-row register window
// (static rotation rw0/rw1/rw2, no copies) -> each T row loaded ONCE, used for 3 outputs.
// Per-thread tile loads 72->36; HBM fetch for the dwconv pair ~207MB -> ~60MB (halo was
// refetched per-h before, and adjacent-h blocks land on different XCDs so L2 didn't dedup).
__device__ __forceinline__ void dw_loadrow(const unsigned short* __restrict__ Tb,
                                           int c0, int w0, int hh, float win[6][4]){
    if (hh < 0 || hh > 127){
        #pragma unroll
        for (int j=0;j<6;j++){ win[j][0]=0.f; win[j][1]=0.f; win[j][2]=0.f; win[j][3]=0.f; }
        return;
    }
    const unsigned short* Tr = Tb + ((size_t)(hh*512))*64 + c0;
    #pragma unroll
    for (int j=0;j<6;j++){
        int ww = w0 - 1 + j;
        if (ww >= 0 && ww < 512){
            uint2 v = *(const uint2*)(Tr + (size_t)ww*64);
            win[j][0] = __uint_as_float(v.x<<16);
            win[j][1] = __uint_as_float(v.x & 0xffff0000u);
            win[j][2] = __uint_as_float(v.y<<16);
            win[j][3] = __uint_as_float(v.y & 0xffff0000u);
        } else {
            win[j][0]=0.f; win[j][1]=0.f; win[j][2]=0.f; win[j][3]=0.f;
        }
    }
}

__device__ __forceinline__ void dw_conv3(const float kw[4][9], const float bv4[4],
                                         const float rA[6][4], const float rB[6][4],
                                         const float rC[6][4], float acc[4][4]){
    #pragma unroll
    for (int ch=0; ch<4; ch++){
        #pragma unroll
        for (int i=0;i<4;i++){
            float a = bv4[ch];
            a += kw[ch][0]*rA[i][ch] + kw[ch][1]*rA[i+1][ch] + kw[ch][2]*rA[i+2][ch];
            a += kw[ch][3]*rB[i][ch] + kw[ch][4]*rB[i+1][ch] + kw[ch][5]*rB[i+2][ch];
            a += kw[ch][6]*rC[i][ch] + kw[ch][7]*rC[i+1][ch] + kw[ch][8]*rC[i+2][ch];
            acc[ch][i] = a;
        }
    }
}

#define HB 4
__global__ __launch_bounds__(256) void dwconv_k(const unsigned short* __restrict__ T1,
                                                const unsigned short* __restrict__ T2,
                                                const float* __restrict__ wd1,
                                                const float* __restrict__ bd1,
                                                const float* __restrict__ wd2,
                                                const float* __restrict__ bd2,
                                                unsigned short* __restrict__ Qdst,
                                                unsigned short* __restrict__ Vdst,
                                                float qscale){
    int bid = blockIdx.x;                       // 512 blocks: 8 wt x 32 hb x 2 b
    int wt = bid & 7, hb = (bid>>3)&31, b = bid>>8;
    int tid = threadIdx.x;
    int cg = tid & 15, wl = tid >> 4;
    int c0 = cg*4;
    int w0 = wt*64 + wl*4;
    int h0 = hb*HB;

    // ---- tile 1: T1 -> Q ([b,hw,c], scaled) ----
    {
        const unsigned short* Tb = T1 + ((size_t)b<<22);
        float kw[4][9], bv4[4];
        #pragma unroll
        for (int ch=0; ch<4; ch++){
            bv4[ch] = bd1[c0+ch];
            #pragma unroll
            for (int t=0;t<9;t++) kw[ch][t] = wd1[(c0+ch)*9 + t];
        }
        float rw0[6][4], rw1[6][4], rw2[6][4];
        dw_loadrow(Tb, c0, w0, h0-1, rw0);
        dw_loadrow(Tb, c0, w0, h0  , rw1);
        float acc[4][4];
        #pragma unroll
        for (int hh=0; hh<HB; hh++){
            // static 3-buffer rotation: (A,B,C) = rw[(hh)%3], rw[(hh+1)%3], rw[(hh+2)%3]
            float (*rA)[4] = (hh%3==0)? rw0 : (hh%3==1)? rw1 : rw2;
            float (*rB)[4] = (hh%3==0)? rw1 : (hh%3==1)? rw2 : rw0;
            float (*rC)[4] = (hh%3==0)? rw2 : (hh%3==1)? rw0 : rw1;
            dw_loadrow(Tb, c0, w0, h0+hh+1, rC);
            dw_conv3(kw, bv4, rA, rB, rC, acc);
            int h = h0 + hh;
            int base = (b*128 + h)*512;
            #pragma unroll
            for (int i=0;i<4;i++){
                uint2 v;
                v.x = pk_rtne(acc[1][i]*qscale, acc[0][i]*qscale);
                v.y = pk_rtne(acc[3][i]*qscale, acc[2][i]*qscale);
                *(uint2*)(Qdst + ((size_t)(base + w0 + i))*64 + c0) = v;
            }
        }
    }

    // ---- tile 2: T2 -> V ([b,c,hw]) ----
    {
        const unsigned short* Tb = T2 + ((size_t)b<<22);
        float kw[4][9], bv4[4];
        #pragma unroll
        for (int ch=0; ch<4; ch++){
            bv4[ch] = bd2[c0+ch];
            #pragma unroll
            for (int t=0;t<9;t++) kw[ch][t] = wd2[(c0+ch)*9 + t];
        }
        float rw0[6][4], rw1[6][4], rw2[6][4];
        dw_loadrow(Tb, c0, w0, h0-1, rw0);
        dw_loadrow(Tb, c0, w0, h0  , rw1);
        float acc[4][4];
        #pragma unroll
        for (int hh=0; hh<HB; hh++){
            float (*rA)[4] = (hh%3==0)? rw0 : (hh%3==1)? rw1 : rw2;
            float (*rB)[4] = (hh%3==0)? rw1 : (hh%3==1)? rw2 : rw0;
            float (*rC)[4] = (hh%3==0)? rw2 : (hh%3==1)? rw0 : rw1;
            dw_loadrow(Tb, c0, w0, h0+hh+1, rC);
            dw_conv3(kw, bv4, rA, rB, rC, acc);
            int h = h0 + hh;
            #pragma unroll
            for (int ch=0; ch<4; ch++){
                uint2 v;
                v.x = pk_rtne(acc[ch][1], acc[ch][0]);
                v.y = pk_rtne(acc[ch][3], acc[ch][2]);
                *(uint2*)(Vdst + (((size_t)(b*64 + c0 + ch))<<16) + h*512 + w0) = v;
            }
        }
    }
}

// ---------------- flash attention + fused output conv1x1, atomic add into out ----------------
// PROVEN 87us version (R2): direct Q loads, in-loop LDS K/V staging, 2 barriers/kt, setprio.
// R1 (reg-prefetch) spilled; R4 (no staging) was L2-latency-bound. Do not re-try those.
#define PQ 72
#define PK 72
#define PV 72
#define PP 72
#define PFA 72
#define POT 17
#define OFF_Q   0        // 128*72*2 = 18432 ; sP/sFA region
#define OFF_K   18432    // 64*72*2 = 9216 ; sOT aliases sK+sV (4*64*17*4 = 17408 <= 18432)
#define OFF_V   27648    // 9216
#define LDS_TOT 36864

__global__ __launch_bounds__(256) void flash_k(
    const unsigned short* __restrict__ Ql, const unsigned short* __restrict__ Qr,
    const unsigned short* __restrict__ Vl, const unsigned short* __restrict__ Vr,
    const float* __restrict__ lw3, const float* __restrict__ lb3,
    const float* __restrict__ rw3, const float* __restrict__ rb3,
    float* __restrict__ out)
{
    __shared__ __align__(16) char smem[LDS_TOT];
    short* sK  = (short*)(smem + OFF_K);
    short* sV  = (short*)(smem + OFF_V);
    short* sP  = (short*)(smem + OFF_Q);   // per-wave 32-row slices
    short* sFA = (short*)(smem + OFF_Q);   // alias (epilogue)
    float* sOT = (float*)(smem + OFF_K);   // alias over sK+sV (epilogue)

    // XCD swizzle: 4 q-tiles of one (dir,b,h) share bid%8 within a 32-block window.
    int bid = blockIdx.x;
    int g  = ((bid >> 5) << 3) | (bid & 7);   // 0..511 = dir*256 + b*128 + h
    int qt = (bid >> 3) & 3;
    int h = g & 127, b = (g >> 7) & 1, dir = g >> 8;
    const unsigned short *Qg, *Kg, *Vg; const float *w3, *b3;
    if (dir==0){ Qg = Ql; Kg = Qr; Vg = Vr; w3 = lw3; b3 = lb3; }
    else       { Qg = Qr; Kg = Ql; Vg = Vl; w3 = rw3; b3 = rb3; }

    int tid = threadIdx.x;
    int wv = tid>>6, lane = tid&63, quad = lane>>4, l16 = lane&15;
    int bh = b*128 + h;

    // Q fragments: direct global loads (wave-private rows; coalesced)
    short8 aq0[2], aq1[2];
    #pragma unroll
    for (int s=0; s<2; s++){
        size_t qrow = ((size_t)bh*512 + qt*128 + wv*32 + s*16 + l16)*64;
        aq0[s] = *(const short8*)(Qg + qrow + quad*8);
        aq1[s] = *(const short8*)(Qg + qrow + 32 + quad*8);
    }

    const f32x4 z4 = {0.f,0.f,0.f,0.f};
    f32x4 oacc[2][4];
    #pragma unroll
    for (int s=0; s<2; s++)
        #pragma unroll
        for (int ct=0; ct<4; ct++) oacc[s][ct] = z4;
    float lps[2] = {0.f, 0.f};

    const uint4* Ksrc = (const uint4*)(Kg + (size_t)bh*512*64);
    const unsigned short* Vbase = Vg + ((size_t)(b*64)*128 + h)*512;

    for (int kt=0; kt<8; kt++){
        #pragma unroll
        for (int it=0; it<2; it++){
            int idx = it*256 + tid;
            int row = idx>>3, piece = idx&7;
            *(uint4*)(sK + row*PK + piece*8) = Ksrc[(size_t)(kt*64 + row)*8 + piece];
            uint4 vv = *(const uint4*)(Vbase + (size_t)row*65536 + kt*64 + piece*8);
            *(uint4*)(sV + row*PV + piece*8) = vv;
        }
        __syncthreads();
        // S^T = K Q^T per q-subtile: D[row=key=nt*16+quad*4+r][col=q=l16]
        #pragma unroll
        for (int nt=0; nt<4; nt++){
            short8 bk0 = *(const short8*)(sK + (nt*16 + l16)*PK + quad*8);
            short8 bk1 = *(const short8*)(sK + (nt*16 + l16)*PK + 32 + quad*8);
            #pragma unroll
            for (int s=0; s<2; s++){
                __builtin_amdgcn_s_setprio(1);
                f32x4 sv = __builtin_amdgcn_mfma_f32_16x16x32_bf16(bk0, aq0[s], z4, 0,0,0);
                sv       = __builtin_amdgcn_mfma_f32_16x16x32_bf16(bk1, aq1[s], sv, 0,0,0);
                __builtin_amdgcn_s_setprio(0);
                float p0 = __builtin_amdgcn_exp2f(sv[0]);
                float p1 = __builtin_amdgcn_exp2f(sv[1]);
                float p2 = __builtin_amdgcn_exp2f(sv[2]);
                float p3 = __builtin_amdgcn_exp2f(sv[3]);
                lps[s] += (p0+p1) + (p2+p3);
                unsigned lo = __builtin_amdgcn_perm(__float_as_uint(p1), __float_as_uint(p0), 0x07060302);
                unsigned hi = __builtin_amdgcn_perm(__float_as_uint(p3), __float_as_uint(p2), 0x07060302);
                uint2 pv; pv.x = lo; pv.y = hi;
                *(uint2*)(sP + (wv*32 + s*16 + l16)*PP + nt*16 + quad*4) = pv;
            }
        }
        // same-wave LDS write->read: no barrier needed (per-wave region)
        short8 ap0[2], ap1[2];
        #pragma unroll
        for (int s=0; s<2; s++){
            ap0[s] = *(const short8*)(sP + (wv*32 + s*16 + l16)*PP + quad*8);
            ap1[s] = *(const short8*)(sP + (wv*32 + s*16 + l16)*PP + 32 + quad*8);
        }
        __builtin_amdgcn_s_setprio(1);
        #pragma unroll
        for (int ct=0; ct<4; ct++){
            short8 bv0 = *(const short8*)(sV + (ct*16 + l16)*PV + quad*8);
            short8 bv1 = *(const short8*)(sV + (ct*16 + l16)*PV + 32 + quad*8);
            #pragma unroll
            for (int s=0; s<2; s++){
                oacc[s][ct] = __builtin_amdgcn_mfma_f32_16x16x32_bf16(ap0[s], bv0, oacc[s][ct], 0,0,0);
                oacc[s][ct] = __builtin_amdgcn_mfma_f32_16x16x32_bf16(ap1[s], bv1, oacc[s][ct], 0,0,0);
            }
        }
        __builtin_amdgcn_s_setprio(0);
        __syncthreads();
    }

    // l(q) reduction
    float inv[2][4];
    #pragma unroll
    for (int s=0; s<2; s++){
        float l = lps[s];
        l += __shfl_xor(l, 16);
        l += __shfl_xor(l, 32);
        #pragma unroll
        for (int r=0;r<4;r++) inv[s][r] = 1.0f / __shfl(l, quad*4 + r);
    }

    // epilogue: F -> LDS (A layout), conv1x1 MFMA with W3 frags from global, bias,
    // LDS transpose, atomic add. Last K-loop barrier guarantees sK/sV dead.
    #pragma unroll
    for (int s=0; s<2; s++){
        short* sFw = sFA + (wv*32 + s*16)*PFA;
        #pragma unroll
        for (int ct=0; ct<4; ct++){
            #pragma unroll
            for (int r=0;r<4;r++)
                sFw[(quad*4+r)*PFA + ct*16 + l16] = (short)f2bf(oacc[s][ct][r]*inv[s][r]);
        }
    }
    short8 af0[2], af1[2];
    #pragma unroll
    for (int s=0; s<2; s++){
        af0[s] = *(const short8*)(sFA + (wv*32 + s*16 + l16)*PFA + quad*8);
        af1[s] = *(const short8*)(sFA + (wv*32 + s*16 + l16)*PFA + 32 + quad*8);
    }
    f32x4 d2[2][4];
    #pragma unroll
    for (int ot=0; ot<4; ot++){
        const float* wrow = w3 + (ot*16 + l16)*64 + quad*8;
        float4 wa = *(const float4*)(wrow);
        float4 wb = *(const float4*)(wrow + 4);
        float4 wc = *(const float4*)(wrow + 32);
        float4 wd = *(const float4*)(wrow + 36);
        short8 bw0, bw1;
        bw0[0]=(short)f2bf(wa.x); bw0[1]=(short)f2bf(wa.y); bw0[2]=(short)f2bf(wa.z); bw0[3]=(short)f2bf(wa.w);
        bw0[4]=(short)f2bf(wb.x); bw0[5]=(short)f2bf(wb.y); bw0[6]=(short)f2bf(wb.z); bw0[7]=(short)f2bf(wb.w);
        bw1[0]=(short)f2bf(wc.x); bw1[1]=(short)f2bf(wc.y); bw1[2]=(short)f2bf(wc.z); bw1[3]=(short)f2bf(wc.w);
        bw1[4]=(short)f2bf(wd.x); bw1[5]=(short)f2bf(wd.y); bw1[6]=(short)f2bf(wd.z); bw1[7]=(short)f2bf(wd.w);
        float bias = b3[ot*16 + l16];
        #pragma unroll
        for (int s=0; s<2; s++){
            d2[s][ot] = __builtin_amdgcn_mfma_f32_16x16x32_bf16(af0[s], bw0, z4, 0,0,0);
            d2[s][ot] = __builtin_amdgcn_mfma_f32_16x16x32_bf16(af1[s], bw1, d2[s][ot], 0,0,0);
            #pragma unroll
            for (int r=0;r<4;r++) d2[s][ot][r] += bias;
        }
    }
    float* sOw = sOT + wv*(64*POT);
    #pragma unroll
    for (int s=0; s<2; s++){
        #pragma unroll
        for (int ot=0; ot<4; ot++){
            #pragma unroll
            for (int r=0;r<4;r++)
                sOw[(ot*16 + l16)*POT + quad*4 + r] = d2[s][ot][r];
        }
        int qbase = qt*128 + wv*32 + s*16;
        #pragma unroll
        for (int it=0; it<16; it++){
            int o = it*4 + quad;
            float val = sOw[o*POT + l16];
            unsafeAtomicAdd(out + ((size_t)(b*64 + o)*128 + h)*512 + qbase + l16, val);
        }
    }
}

extern "C" void kernel_launch(void* const* d_in, const int* in_sizes, int n_in,
                              void* d_out, int out_size, void* d_ws, size_t ws_size,
                              hipStream_t stream)
{
    const float* xl = (const float*)d_in[0];
    const float* xr = (const float*)d_in[1];
    const float* lp1_w1 = (const float*)d_in[2];
    const float* lp1_b1 = (const float*)d_in[3];
    const float* lp1_wd = (const float*)d_in[4];
    const float* lp1_bd = (const float*)d_in[5];
    const float* rp1_w1 = (const float*)d_in[6];
    const float* rp1_b1 = (const float*)d_in[7];
    const float* rp1_wd = (const float*)d_in[8];
    const float* rp1_bd = (const float*)d_in[9];
    const float* lp2_w1 = (const float*)d_in[10];
    const float* lp2_b1 = (const float*)d_in[11];
    const float* lp2_wd = (const float*)d_in[12];
    const float* lp2_bd = (const float*)d_in[13];
    const float* rp2_w1 = (const float*)d_in[14];
    const float* rp2_b1 = (const float*)d_in[15];
    const float* rp2_wd = (const float*)d_in[16];
    const float* rp2_bd = (const float*)d_in[17];
    const float* lp3_w  = (const float*)d_in[18];
    const float* lp3_b  = (const float*)d_in[19];
    const float* rp3_w  = (const float*)d_in[20];
    const float* rp3_b  = (const float*)d_in[21];
    float* out = (float*)d_out;

    // 6 slots of 16 MiB (96 MiB). Choreography (no Xt intermediate):
    //  prepgemm: writes T1L->s2, T2L->s3, T1R->s4, T2R->s5  (s0,s1 free)
    //  dwL: reads s2,s3 -> Ql s0, Vl s1
    //  dwR: reads s4,s5 -> Qr s2, Vr s3 (T1L/T2L dead after dwL)
    //  flash: reads s0,s2,s1,s3
    const size_t S = 16777216;
    char* ws = (char*)d_ws;
    unsigned short* s0 = (unsigned short*)(ws);
    unsigned short* s1 = (unsigned short*)(ws + 1*S);
    unsigned short* s2 = (unsigned short*)(ws + 2*S);
    unsigned short* s3 = (unsigned short*)(ws + 3*S);
    unsigned short* s4 = (unsigned short*)(ws + 4*S);
    unsigned short* s5 = (unsigned short*)(ws + 5*S);

    prepgemm_k<<<1024, 256, 0, stream>>>(xl, xr, out,
        lp1_w1, lp1_b1, lp2_w1, lp2_b1,
        rp1_w1, rp1_b1, rp2_w1, rp2_b1,
        /*T1L*/s2, /*T2L*/s3, /*T1R*/s4, /*T2R*/s5);

    dwconv_k<<<512, 256, 0, stream>>>(/*T1L*/s2, /*T2L*/s3,
        lp1_wd, lp1_bd, lp2_wd, lp2_bd, /*Ql*/s0, /*Vl*/s1, QSCALE);

    dwconv_k<<<512, 256, 0, stream>>>(/*T1R*/s4, /*T2R*/s5,
        rp1_wd, rp1_bd, rp2_wd, rp2_bd, /*Qr*/s2, /*Vr*/s3, 1.0f);

    flash_k<<<2048, 256, 0, stream>>>(/*Ql*/s0, /*Qr*/s2, /*Vl*/s1, /*Vr*/s3,
        lp3_w, lp3_b, rp3_w, rp3_b, out);
}

// Round 12
// 302.091 us; speedup vs baseline: 1.3007x; 1.0040x over previous
//
#include <hip/hip_runtime.h>
#include <hip/hip_bf16.h>

typedef __attribute__((ext_vector_type(8))) short short8;
typedef __attribute__((ext_vector_type(4))) float f32x4;

// SCALE * log2(e), folded into Ql at store time; flash uses exp2 directly.
#define QSCALE 0.18033688011112042f

__device__ __forceinline__ unsigned short f2bf(float f){
    unsigned u = __float_as_uint(f);
    unsigned r = (u + 0x7fffu + ((u>>16)&1u))>>16;
    return (unsigned short)r;
}
__device__ __forceinline__ unsigned pk_rtne(float hi, float lo){
    return (((unsigned)f2bf(hi))<<16) | (unsigned)f2bf(lo);
}

// ---------------- fused prep+gemm: out = xl+xr; T1/T2 = dwconv-input conv1x1 outputs, both sides ----
// (unchanged - measured good: kills 67MB Xt round-trip, total 324->309us)
__global__ __launch_bounds__(256) void prepgemm_k(const float* __restrict__ xl,
                                                  const float* __restrict__ xr,
                                                  float* __restrict__ out,
                                                  const float* __restrict__ wAL, const float* __restrict__ bAL,
                                                  const float* __restrict__ wBL, const float* __restrict__ bBL,
                                                  const float* __restrict__ wAR, const float* __restrict__ bAR,
                                                  const float* __restrict__ wBR, const float* __restrict__ bBR,
                                                  unsigned short* __restrict__ T1L, unsigned short* __restrict__ T2L,
                                                  unsigned short* __restrict__ T1R, unsigned short* __restrict__ T2R){
    __shared__ float ftA[64*130];
    __shared__ __align__(16) short sB[128*72];
    __shared__ float sbias[128];

    int bid = blockIdx.x;
    int b = bid >> 9, px0 = (bid & 511) << 7;
    int tid = threadIdx.x;
    int wv = tid>>6, lane = tid&63, quad = lane>>4, l16 = lane&15;

    // ---- phase 1: load xl+xr strip, write out, stage xl (fp32) + weights L ----
    float4 vxr[8];
    #pragma unroll
    for (int it=0; it<8; it++){
        int lin = it*256 + tid;             // 2048 float4 = 64c x 128px
        int c = lin >> 5, piece = lin & 31;
        size_t off = (((size_t)(b*64 + c))<<16) + px0 + piece*4;
        float4 va = *(const float4*)(xl + off);
        float4 vb = *(const float4*)(xr + off);
        vxr[it] = vb;
        float4 vo; vo.x=va.x+vb.x; vo.y=va.y+vb.y; vo.z=va.z+vb.z; vo.w=va.w+vb.w;
        *(float4*)(out + off) = vo;
        float* d = ftA + c*130 + piece*4;
        float2 lo; lo.x=va.x; lo.y=va.y;
        float2 hi; hi.x=va.z; hi.y=va.w;
        *(float2*)(d) = lo;
        *(float2*)(d+2) = hi;
    }
    {   // weights L -> sB (128 out x 64 in, bf16, pitch 72)
        #pragma unroll
        for (int it=0; it<8; it++){
            int lin = it*256 + tid;          // 2048 float4 = 8192 floats
            int o = lin >> 4, cc4 = (lin & 15) << 2;
            const float* wsrc = (o < 64) ? (wAL + o*64 + cc4) : (wBL + (o-64)*64 + cc4);
            float4 w4 = *(const float4*)wsrc;
            uint2 v; v.x = pk_rtne(w4.y, w4.x); v.y = pk_rtne(w4.w, w4.z);
            *(uint2*)(sB + o*72 + cc4) = v;
        }
        if (tid < 128) sbias[tid] = (tid < 64) ? bAL[tid] : bBL[tid-64];
    }
    __syncthreads();

    const f32x4 z4 = {0.f,0.f,0.f,0.f};

    // ---- per-side GEMM macro body (wave owns 32 px rows: wv*32 + mt*16 + l16) ----
    #define DO_GEMM(T1p, T2p) do {                                                  \
        short8 a0[2], a1[2];                                                        \
        _Pragma("unroll")                                                           \
        for (int mt=0; mt<2; mt++){                                                 \
            int pxr = wv*32 + mt*16 + l16;                                          \
            _Pragma("unroll")                                                       \
            for (int j=0;j<8;j++){                                                  \
                a0[mt][j] = (short)f2bf(ftA[(quad*8 + j)*130 + pxr]);               \
                a1[mt][j] = (short)f2bf(ftA[(32 + quad*8 + j)*130 + pxr]);          \
            }                                                                       \
        }                                                                           \
        _Pragma("unroll")                                                           \
        for (int set=0; set<2; set++){                                              \
            unsigned short* T = set ? (T2p) : (T1p);                                \
            short8 bB0[4], bB1[4];                                                  \
            _Pragma("unroll")                                                       \
            for (int nt=0; nt<4; nt++){                                             \
                bB0[nt] = *(const short8*)(sB + (set*64 + nt*16 + l16)*72 + quad*8);      \
                bB1[nt] = *(const short8*)(sB + (set*64 + nt*16 + l16)*72 + 32 + quad*8); \
            }                                                                       \
            _Pragma("unroll")                                                       \
            for (int nt=0; nt<4; nt++){                                             \
                float4 b4 = *(const float4*)(sbias + set*64 + nt*16 + quad*4);      \
                _Pragma("unroll")                                                   \
                for (int mt=0; mt<2; mt++){                                         \
                    f32x4 acc = __builtin_amdgcn_mfma_f32_16x16x32_bf16(bB0[nt], a0[mt], z4, 0,0,0); \
                    acc       = __builtin_amdgcn_mfma_f32_16x16x32_bf16(bB1[nt], a1[mt], acc, 0,0,0); \
                    uint2 v;                                                        \
                    v.x = pk_rtne(acc[1]+b4.y, acc[0]+b4.x);                        \
                    v.y = pk_rtne(acc[3]+b4.w, acc[2]+b4.z);                        \
                    int px = px0 + wv*32 + mt*16 + l16;                             \
                    *(uint2*)(T + (size_t)px*64 + nt*16 + quad*4) = v;              \
                }                                                                   \
            }                                                                       \
        }                                                                           \
    } while(0)

    // ---- phase 2: GEMM side L ----
    DO_GEMM(T1L + ((size_t)b<<22), T2L + ((size_t)b<<22));
    __syncthreads();

    // ---- phase 3: restage xr + weights R ----
    #pragma unroll
    for (int it=0; it<8; it++){
        int lin = it*256 + tid;
        int c = lin >> 5, piece = lin & 31;
        float4 vb = vxr[it];
        float* d = ftA + c*130 + piece*4;
        float2 lo; lo.x=vb.x; lo.y=vb.y;
        float2 hi; hi.x=vb.z; hi.y=vb.w;
        *(float2*)(d) = lo;
        *(float2*)(d+2) = hi;
    }
    {
        #pragma unroll
        for (int it=0; it<8; it++){
            int lin = it*256 + tid;
            int o = lin >> 4, cc4 = (lin & 15) << 2;
            const float* wsrc = (o < 64) ? (wAR + o*64 + cc4) : (wBR + (o-64)*64 + cc4);
            float4 w4 = *(const float4*)wsrc;
            uint2 v; v.x = pk_rtne(w4.y, w4.x); v.y = pk_rtne(w4.w, w4.z);
            *(uint2*)(sB + o*72 + cc4) = v;
        }
        if (tid < 128) sbias[tid] = (tid < 64) ? bAR[tid] : bBR[tid-64];
    }
    __syncthreads();

    // ---- phase 4: GEMM side R ----
    DO_GEMM(T1R + ((size_t)b<<22), T2R + ((size_t)b<<22));
    #undef DO_GEMM
}

// ---------------- dual depthwise 3x3, 4-h strip + rolling window, T1/T2 SPLIT across blocks ----
// R7 change: R5 cut grid 2048->512 (2 blocks/CU) - halo savings were canceled by lost TLP.
// Now tile-split: half the blocks do T1->Q, half do T2->V. Grid 1024 = 4 blocks/CU, same
// traffic/reuse, half the register state per block, 2x independent streams for latency hiding.
__device__ __forceinline__ void dw_loadrow(const unsigned short* __restrict__ Tb,
                                           int c0, int w0, int hh, float win[6][4]){
    if (hh < 0 || hh > 127){
        #pragma unroll
        for (int j=0;j<6;j++){ win[j][0]=0.f; win[j][1]=0.f; win[j][2]=0.f; win[j][3]=0.f; }
        return;
    }
    const unsigned short* Tr = Tb + ((size_t)(hh*512))*64 + c0;
    #pragma unroll
    for (int j=0;j<6;j++){
        int ww = w0 - 1 + j;
        if (ww >= 0 && ww < 512){
            uint2 v = *(const uint2*)(Tr + (size_t)ww*64);
            win[j][0] = __uint_as_float(v.x<<16);
            win[j][1] = __uint_as_float(v.x & 0xffff0000u);
            win[j][2] = __uint_as_float(v.y<<16);
            win[j][3] = __uint_as_float(v.y & 0xffff0000u);
        } else {
            win[j][0]=0.f; win[j][1]=0.f; win[j][2]=0.f; win[j][3]=0.f;
        }
    }
}

__device__ __forceinline__ void dw_conv3(const float kw[4][9], const float bv4[4],
                                         const float rA[6][4], const float rB[6][4],
                                         const float rC[6][4], float acc[4][4]){
    #pragma unroll
    for (int ch=0; ch<4; ch++){
        #pragma unroll
        for (int i=0;i<4;i++){
            float a = bv4[ch];
            a += kw[ch][0]*rA[i][ch] + kw[ch][1]*rA[i+1][ch] + kw[ch][2]*rA[i+2][ch];
            a += kw[ch][3]*rB[i][ch] + kw[ch][4]*rB[i+1][ch] + kw[ch][5]*rB[i+2][ch];
            a += kw[ch][6]*rC[i][ch] + kw[ch][7]*rC[i+1][ch] + kw[ch][8]*rC[i+2][ch];
            acc[ch][i] = a;
        }
    }
}

#define HB 4
__global__ __launch_bounds__(256) void dwconv_k(const unsigned short* __restrict__ T1,
                                                const unsigned short* __restrict__ T2,
                                                const float* __restrict__ wd1,
                                                const float* __restrict__ bd1,
                                                const float* __restrict__ wd2,
                                                const float* __restrict__ bd2,
                                                unsigned short* __restrict__ Qdst,
                                                unsigned short* __restrict__ Vdst,
                                                float qscale){
    int bid = blockIdx.x;                       // 1024 blocks: 8 wt x 32 hb x 2 b x 2 tile
    int wt = bid & 7, hb = (bid>>3)&31, b = (bid>>8)&1, tsel = bid>>9;
    int tid = threadIdx.x;
    int cg = tid & 15, wl = tid >> 4;
    int c0 = cg*4;
    int w0 = wt*64 + wl*4;
    int h0 = hb*HB;

    if (tsel == 0){
        // ---- T1 -> Q ([b,hw,c], scaled) ----
        const unsigned short* Tb = T1 + ((size_t)b<<22);
        float kw[4][9], bv4[4];
        #pragma unroll
        for (int ch=0; ch<4; ch++){
            bv4[ch] = bd1[c0+ch];
            #pragma unroll
            for (int t=0;t<9;t++) kw[ch][t] = wd1[(c0+ch)*9 + t];
        }
        float rw0[6][4], rw1[6][4], rw2[6][4];
        dw_loadrow(Tb, c0, w0, h0-1, rw0);
        dw_loadrow(Tb, c0, w0, h0  , rw1);
        float acc[4][4];
        #pragma unroll
        for (int hh=0; hh<HB; hh++){
            // static 3-buffer rotation
            float (*rA)[4] = (hh%3==0)? rw0 : (hh%3==1)? rw1 : rw2;
            float (*rB)[4] = (hh%3==0)? rw1 : (hh%3==1)? rw2 : rw0;
            float (*rC)[4] = (hh%3==0)? rw2 : (hh%3==1)? rw0 : rw1;
            dw_loadrow(Tb, c0, w0, h0+hh+1, rC);
            dw_conv3(kw, bv4, rA, rB, rC, acc);
            int h = h0 + hh;
            int base = (b*128 + h)*512;
            #pragma unroll
            for (int i=0;i<4;i++){
                uint2 v;
                v.x = pk_rtne(acc[1][i]*qscale, acc[0][i]*qscale);
                v.y = pk_rtne(acc[3][i]*qscale, acc[2][i]*qscale);
                *(uint2*)(Qdst + ((size_t)(base + w0 + i))*64 + c0) = v;
            }
        }
    } else {
        // ---- T2 -> V ([b,c,hw]) ----
        const unsigned short* Tb = T2 + ((size_t)b<<22);
        float kw[4][9], bv4[4];
        #pragma unroll
        for (int ch=0; ch<4; ch++){
            bv4[ch] = bd2[c0+ch];
            #pragma unroll
            for (int t=0;t<9;t++) kw[ch][t] = wd2[(c0+ch)*9 + t];
        }
        float rw0[6][4], rw1[6][4], rw2[6][4];
        dw_loadrow(Tb, c0, w0, h0-1, rw0);
        dw_loadrow(Tb, c0, w0, h0  , rw1);
        float acc[4][4];
        #pragma unroll
        for (int hh=0; hh<HB; hh++){
            float (*rA)[4] = (hh%3==0)? rw0 : (hh%3==1)? rw1 : rw2;
            float (*rB)[4] = (hh%3==0)? rw1 : (hh%3==1)? rw2 : rw0;
            float (*rC)[4] = (hh%3==0)? rw2 : (hh%3==1)? rw0 : rw1;
            dw_loadrow(Tb, c0, w0, h0+hh+1, rC);
            dw_conv3(kw, bv4, rA, rB, rC, acc);
            int h = h0 + hh;
            #pragma unroll
            for (int ch=0; ch<4; ch++){
                uint2 v;
                v.x = pk_rtne(acc[ch][1], acc[ch][0]);
                v.y = pk_rtne(acc[ch][3], acc[ch][2]);
                *(uint2*)(Vdst + (((size_t)(b*64 + c0 + ch))<<16) + h*512 + w0) = v;
            }
        }
    }
}

// ---------------- flash attention + fused output conv1x1, atomic add into out ----------------
// PROVEN 87us version (R2): direct Q loads, in-loop LDS K/V staging, 2 barriers/kt, setprio.
// R1 (reg-prefetch) spilled; R4 (no staging) was L2-latency-bound. Do not re-try those.
#define PQ 72
#define PK 72
#define PV 72
#define PP 72
#define PFA 72
#define POT 17
#define OFF_Q   0        // 128*72*2 = 18432 ; sP/sFA region
#define OFF_K   18432    // 64*72*2 = 9216 ; sOT aliases sK+sV (4*64*17*4 = 17408 <= 18432)
#define OFF_V   27648    // 9216
#define LDS_TOT 36864

__global__ __launch_bounds__(256) void flash_k(
    const unsigned short* __restrict__ Ql, const unsigned short* __restrict__ Qr,
    const unsigned short* __restrict__ Vl, const unsigned short* __restrict__ Vr,
    const float* __restrict__ lw3, const float* __restrict__ lb3,
    const float* __restrict__ rw3, const float* __restrict__ rb3,
    float* __restrict__ out)
{
    __shared__ __align__(16) char smem[LDS_TOT];
    short* sK  = (short*)(smem + OFF_K);
    short* sV  = (short*)(smem + OFF_V);
    short* sP  = (short*)(smem + OFF_Q);   // per-wave 32-row slices
    short* sFA = (short*)(smem + OFF_Q);   // alias (epilogue)
    float* sOT = (float*)(smem + OFF_K);   // alias over sK+sV (epilogue)

    // XCD swizzle: 4 q-tiles of one (dir,b,h) share bid%8 within a 32-block window.
    int bid = blockIdx.x;
    int g  = ((bid >> 5) << 3) | (bid & 7);   // 0..511 = dir*256 + b*128 + h
    int qt = (bid >> 3) & 3;
    int h = g & 127, b = (g >> 7) & 1, dir = g >> 8;
    const unsigned short *Qg, *Kg, *Vg; const float *w3, *b3;
    if (dir==0){ Qg = Ql; Kg = Qr; Vg = Vr; w3 = lw3; b3 = lb3; }
    else       { Qg = Qr; Kg = Ql; Vg = Vl; w3 = rw3; b3 = rb3; }

    int tid = threadIdx.x;
    int wv = tid>>6, lane = tid&63, quad = lane>>4, l16 = lane&15;
    int bh = b*128 + h;

    // Q fragments: direct global loads (wave-private rows; coalesced)
    short8 aq0[2], aq1[2];
    #pragma unroll
    for (int s=0; s<2; s++){
        size_t qrow = ((size_t)bh*512 + qt*128 + wv*32 + s*16 + l16)*64;
        aq0[s] = *(const short8*)(Qg + qrow + quad*8);
        aq1[s] = *(const short8*)(Qg + qrow + 32 + quad*8);
    }

    const f32x4 z4 = {0.f,0.f,0.f,0.f};
    f32x4 oacc[2][4];
    #pragma unroll
    for (int s=0; s<2; s++)
        #pragma unroll
        for (int ct=0; ct<4; ct++) oacc[s][ct] = z4;
    float lps[2] = {0.f, 0.f};

    const uint4* Ksrc = (const uint4*)(Kg + (size_t)bh*512*64);
    const unsigned short* Vbase = Vg + ((size_t)(b*64)*128 + h)*512;

    for (int kt=0; kt<8; kt++){
        #pragma unroll
        for (int it=0; it<2; it++){
            int idx = it*256 + tid;
            int row = idx>>3, piece = idx&7;
            *(uint4*)(sK + row*PK + piece*8) = Ksrc[(size_t)(kt*64 + row)*8 + piece];
            uint4 vv = *(const uint4*)(Vbase + (size_t)row*65536 + kt*64 + piece*8);
            *(uint4*)(sV + row*PV + piece*8) = vv;
        }
        __syncthreads();
        // S^T = K Q^T per q-subtile: D[row=key=nt*16+quad*4+r][col=q=l16]
        #pragma unroll
        for (int nt=0; nt<4; nt++){
            short8 bk0 = *(const short8*)(sK + (nt*16 + l16)*PK + quad*8);
            short8 bk1 = *(const short8*)(sK + (nt*16 + l16)*PK + 32 + quad*8);
            #pragma unroll
            for (int s=0; s<2; s++){
                __builtin_amdgcn_s_setprio(1);
                f32x4 sv = __builtin_amdgcn_mfma_f32_16x16x32_bf16(bk0, aq0[s], z4, 0,0,0);
                sv       = __builtin_amdgcn_mfma_f32_16x16x32_bf16(bk1, aq1[s], sv, 0,0,0);
                __builtin_amdgcn_s_setprio(0);
                float p0 = __builtin_amdgcn_exp2f(sv[0]);
                float p1 = __builtin_amdgcn_exp2f(sv[1]);
                float p2 = __builtin_amdgcn_exp2f(sv[2]);
                float p3 = __builtin_amdgcn_exp2f(sv[3]);
                lps[s] += (p0+p1) + (p2+p3);
                unsigned lo = __builtin_amdgcn_perm(__float_as_uint(p1), __float_as_uint(p0), 0x07060302);
                unsigned hi = __builtin_amdgcn_perm(__float_as_uint(p3), __float_as_uint(p2), 0x07060302);
                uint2 pv; pv.x = lo; pv.y = hi;
                *(uint2*)(sP + (wv*32 + s*16 + l16)*PP + nt*16 + quad*4) = pv;
            }
        }
        // same-wave LDS write->read: no barrier needed (per-wave region)
        short8 ap0[2], ap1[2];
        #pragma unroll
        for (int s=0; s<2; s++){
            ap0[s] = *(const short8*)(sP + (wv*32 + s*16 + l16)*PP + quad*8);
            ap1[s] = *(const short8*)(sP + (wv*32 + s*16 + l16)*PP + 32 + quad*8);
        }
        __builtin_amdgcn_s_setprio(1);
        #pragma unroll
        for (int ct=0; ct<4; ct++){
            short8 bv0 = *(const short8*)(sV + (ct*16 + l16)*PV + quad*8);
            short8 bv1 = *(const short8*)(sV + (ct*16 + l16)*PV + 32 + quad*8);
            #pragma unroll
            for (int s=0; s<2; s++){
                oacc[s][ct] = __builtin_amdgcn_mfma_f32_16x16x32_bf16(ap0[s], bv0, oacc[s][ct], 0,0,0);
                oacc[s][ct] = __builtin_amdgcn_mfma_f32_16x16x32_bf16(ap1[s], bv1, oacc[s][ct], 0,0,0);
            }
        }
        __builtin_amdgcn_s_setprio(0);
        __syncthreads();
    }

    // l(q) reduction
    float inv[2][4];
    #pragma unroll
    for (int s=0; s<2; s++){
        float l = lps[s];
        l += __shfl_xor(l, 16);
        l += __shfl_xor(l, 32);
        #pragma unroll
        for (int r=0;r<4;r++) inv[s][r] = 1.0f / __shfl(l, quad*4 + r);
    }

    // epilogue: F -> LDS (A layout), conv1x1 MFMA with W3 frags from global, bias,
    // LDS transpose, atomic add. Last K-loop barrier guarantees sK/sV dead.
    #pragma unroll
    for (int s=0; s<2; s++){
        short* sFw = sFA + (wv*32 + s*16)*PFA;
        #pragma unroll
        for (int ct=0; ct<4; ct++){
            #pragma unroll
            for (int r=0;r<4;r++)
                sFw[(quad*4+r)*PFA + ct*16 + l16] = (short)f2bf(oacc[s][ct][r]*inv[s][r]);
        }
    }
    short8 af0[2], af1[2];
    #pragma unroll
    for (int s=0; s<2; s++){
        af0[s] = *(const short8*)(sFA + (wv*32 + s*16 + l16)*PFA + quad*8);
        af1[s] = *(const short8*)(sFA + (wv*32 + s*16 + l16)*PFA + 32 + quad*8);
    }
    f32x4 d2[2][4];
    #pragma unroll
    for (int ot=0; ot<4; ot++){
        const float* wrow = w3 + (ot*16 + l16)*64 + quad*8;
        float4 wa = *(const float4*)(wrow);
        float4 wb = *(const float4*)(wrow + 4);
        float4 wc = *(const float4*)(wrow + 32);
        float4 wd = *(const float4*)(wrow + 36);
        short8 bw0, bw1;
        bw0[0]=(short)f2bf(wa.x); bw0[1]=(short)f2bf(wa.y); bw0[2]=(short)f2bf(wa.z); bw0[3]=(short)f2bf(wa.w);
        bw0[4]=(short)f2bf(wb.x); bw0[5]=(short)f2bf(wb.y); bw0[6]=(short)f2bf(wb.z); bw0[7]=(short)f2bf(wb.w);
        bw1[0]=(short)f2bf(wc.x); bw1[1]=(short)f2bf(wc.y); bw1[2]=(short)f2bf(wc.z); bw1[3]=(short)f2bf(wc.w);
        bw1[4]=(short)f2bf(wd.x); bw1[5]=(short)f2bf(wd.y); bw1[6]=(short)f2bf(wd.z); bw1[7]=(short)f2bf(wd.w);
        float bias = b3[ot*16 + l16];
        #pragma unroll
        for (int s=0; s<2; s++){
            d2[s][ot] = __builtin_amdgcn_mfma_f32_16x16x32_bf16(af0[s], bw0, z4, 0,0,0);
            d2[s][ot] = __builtin_amdgcn_mfma_f32_16x16x32_bf16(af1[s], bw1, d2[s][ot], 0,0,0);
            #pragma unroll
            for (int r=0;r<4;r++) d2[s][ot][r] += bias;
        }
    }
    float* sOw = sOT + wv*(64*POT);
    #pragma unroll
    for (int s=0; s<2; s++){
        #pragma unroll
        for (int ot=0; ot<4; ot++){
            #pragma unroll
            for (int r=0;r<4;r++)
                sOw[(ot*16 + l16)*POT + quad*4 + r] = d2[s][ot][r];
        }
        int qbase = qt*128 + wv*32 + s*16;
        #pragma unroll
        for (int it=0; it<16; it++){
            int o = it*4 + quad;
            float val = sOw[o*POT + l16];
            unsafeAtomicAdd(out + ((size_t)(b*64 + o)*128 + h)*512 + qbase + l16, val);
        }
    }
}

extern "C" void kernel_launch(void* const* d_in, const int* in_sizes, int n_in,
                              void* d_out, int out_size, void* d_ws, size_t ws_size,
                              hipStream_t stream)
{
    const float* xl = (const float*)d_in[0];
    const float* xr = (const float*)d_in[1];
    const float* lp1_w1 = (const float*)d_in[2];
    const float* lp1_b1 = (const float*)d_in[3];
    const float* lp1_wd = (const float*)d_in[4];
    const float* lp1_bd = (const float*)d_in[5];
    const float* rp1_w1 = (const float*)d_in[6];
    const float* rp1_b1 = (const float*)d_in[7];
    const float* rp1_wd = (const float*)d_in[8];
    const float* rp1_bd = (const float*)d_in[9];
    const float* lp2_w1 = (const float*)d_in[10];
    const float* lp2_b1 = (const float*)d_in[11];
    const float* lp2_wd = (const float*)d_in[12];
    const float* lp2_bd = (const float*)d_in[13];
    const float* rp2_w1 = (const float*)d_in[14];
    const float* rp2_b1 = (const float*)d_in[15];
    const float* rp2_wd = (const float*)d_in[16];
    const float* rp2_bd = (const float*)d_in[17];
    const float* lp3_w  = (const float*)d_in[18];
    const float* lp3_b  = (const float*)d_in[19];
    const float* rp3_w  = (const float*)d_in[20];
    const float* rp3_b  = (const float*)d_in[21];
    float* out = (float*)d_out;

    // 6 slots of 16 MiB (96 MiB). Choreography (no Xt intermediate):
    //  prepgemm: writes T1L->s2, T2L->s3, T1R->s4, T2R->s5  (s0,s1 free)
    //  dwL: reads s2,s3 -> Ql s0, Vl s1
    //  dwR: reads s4,s5 -> Qr s2, Vr s3 (T1L/T2L dead after dwL)
    //  flash: reads s0,s2,s1,s3
    const size_t S = 16777216;
    char* ws = (char*)d_ws;
    unsigned short* s0 = (unsigned short*)(ws);
    unsigned short* s1 = (unsigned short*)(ws + 1*S);
    unsigned short* s2 = (unsigned short*)(ws + 2*S);
    unsigned short* s3 = (unsigned short*)(ws + 3*S);
    unsigned short* s4 = (unsigned short*)(ws + 4*S);
    unsigned short* s5 = (unsigned short*)(ws + 5*S);

    prepgemm_k<<<1024, 256, 0, stream>>>(xl, xr, out,
        lp1_w1, lp1_b1, lp2_w1, lp2_b1,
        rp1_w1, rp1_b1, rp2_w1, rp2_b1,
        /*T1L*/s2, /*T2L*/s3, /*T1R*/s4, /*T2R*/s5);

    dwconv_k<<<1024, 256, 0, stream>>>(/*T1L*/s2, /*T2L*/s3,
        lp1_wd, lp1_bd, lp2_wd, lp2_bd, /*Ql*/s0, /*Vl*/s1, QSCALE);

    dwconv_k<<<1024, 256, 0, stream>>>(/*T1R*/s4, /*T2R*/s5,
        rp1_wd, rp1_bd, rp2_wd, rp2_bd, /*Qr*/s2, /*Vr*/s3, 1.0f);

    flash_k<<<2048, 256, 0, stream>>>(/*Ql*/s0, /*Qr*/s2, /*Vl*/s1, /*Vr*/s3,
        lp3_w, lp3_b, rp3_w, rp3_b, out);
}